// Round 10
// baseline (208.660 us; speedup 1.0000x reference)
//
#include <hip/hip_runtime.h>
#include <cstddef>

#define NREL 8
#define SCAN_TILE 4096

typedef __bf16 bf16x8 __attribute__((ext_vector_type(8)));
typedef float f32x4 __attribute__((ext_vector_type(4)));

__device__ __forceinline__ unsigned f2bf_u(float f) {
    unsigned u = __float_as_uint(f);
    u += 0x7FFFu + ((u >> 16) & 1u);           // RNE
    return u >> 16;
}
__device__ __forceinline__ short f2bf(float f) { return (short)f2bf_u(f); }
__device__ __forceinline__ int pack2bf(float lo, float hi) {
    return (int)(f2bf_u(lo) | (f2bf_u(hi) << 16));
}
__device__ __forceinline__ float bfval(unsigned short g) {
    return __uint_as_float((unsigned)g << 16);
}

// ---------------------------------------------------------------------------
// K1: zero cursor/cnt8 + offs[N] = E
// ---------------------------------------------------------------------------
__global__ __launch_bounds__(256) void zero_kernel(int4* __restrict__ p, int n16,
                                                   int* __restrict__ offsN, int E)
{
    int i = blockIdx.x * 256 + threadIdx.x;
    if (i < n16) p[i] = make_int4(0, 0, 0, 0);
    if (i == 0) *offsN = E;
}

// ---------------------------------------------------------------------------
// device bodies for fused prep
// ---------------------------------------------------------------------------
template<int K>
__device__ __forceinline__ void wfrag_body(const float* __restrict__ basis,
                                           const float* __restrict__ root,
                                           const float* __restrict__ comp,
                                           short* __restrict__ Wf, int tid)
{
    constexpr int NK = K / 32;
    int lane = tid & 63, slot = tid >> 6;
    int ks = slot % NK, t = slot / NK;
    int kg = lane >> 4, lr = lane & 15;
    int k0 = ks * 32 + kg * 8;
    union { short s[8]; int4 v; } u;
#pragma unroll
    for (int e = 0; e < 8; ++e) {
        int k = k0 + e;
        float v;
        if (t < 32) {
            int rr = t >> 2, ch = (t & 3) * 16 + lr;
            v = comp[rr * 4 + 0] * basis[((size_t)0 * K + k) * 64 + ch]
              + comp[rr * 4 + 1] * basis[((size_t)1 * K + k) * 64 + ch]
              + comp[rr * 4 + 2] * basis[((size_t)2 * K + k) * 64 + ch]
              + comp[rr * 4 + 3] * basis[((size_t)3 * K + k) * 64 + ch];
        } else {
            v = root[(size_t)k * 64 + (t - 32) * 16 + lr];
        }
        u.s[e] = f2bf(v);
    }
    *(int4*)(Wf + (size_t)tid * 8) = u.v;
}

__device__ __forceinline__ void afrag_body128(const float* __restrict__ x,
                                              short* __restrict__ xf, int N, int tid)
{
    int lane = tid & 63, slot = tid >> 6;
    int ks = slot & 3, rt = slot >> 2;
    int kg = lane >> 4, lr = lane & 15;
    int row = rt * 16 + lr, k = ks * 32 + kg * 8;
    union { short s[8]; int4 v; } u;
    if (row < N) {
        const float* xp = x + (size_t)row * 128 + k;
        float4 a = *(const float4*)xp;
        float4 b = *(const float4*)(xp + 4);
        u.s[0] = f2bf(a.x); u.s[1] = f2bf(a.y); u.s[2] = f2bf(a.z); u.s[3] = f2bf(a.w);
        u.s[4] = f2bf(b.x); u.s[5] = f2bf(b.y); u.s[6] = f2bf(b.z); u.s[7] = f2bf(b.w);
    } else {
        u.v = make_int4(0, 0, 0, 0);
    }
    *(int4*)(xf + (size_t)tid * 8) = u.v;
}

// ---------------------------------------------------------------------------
// K2: fused { hist | wfrag1 | wfrag2 | afrag(x) } — all independent
// ---------------------------------------------------------------------------
__global__ __launch_bounds__(256) void prep_hist_kernel(
    const int* __restrict__ dstp, const int* __restrict__ et, int* __restrict__ cnt8,
    const float* __restrict__ basis1, const float* __restrict__ root1,
    const float* __restrict__ comp1,  const float* __restrict__ basis2,
    const float* __restrict__ root2,  const float* __restrict__ comp2,
    const float* __restrict__ x,
    short* __restrict__ Wf1, short* __restrict__ Wf2, short* __restrict__ xf1,
    int E, int N, int NT, int HB)
{
    int b = blockIdx.x;
    if (b < HB) {
        int e = b * 256 + threadIdx.x;
        if (e < E) atomicAdd(&cnt8[dstp[e] * NREL + et[e]], 1);
        return;
    }
    b -= HB;
    if (b < 36) { wfrag_body<128>(basis1, root1, comp1, Wf1, b * 256 + threadIdx.x); return; }
    b -= 36;
    if (b < 18) { wfrag_body<64>(basis2, root2, comp2, Wf2, b * 256 + threadIdx.x); return; }
    b -= 18;
    int tid = b * 256 + threadIdx.x;
    if (tid < NT * 256) afrag_body128(x, xf1, N, tid);
}

// ---------------------------------------------------------------------------
// Scan stage 1: per-tile degree sums
// ---------------------------------------------------------------------------
__global__ __launch_bounds__(256) void scan_part(const int* __restrict__ cnt8,
                                                 int* __restrict__ tsum, int n)
{
    int base = blockIdx.x * SCAN_TILE;
    int s = 0;
    for (int i = threadIdx.x; i < SCAN_TILE; i += 256) {
        int idx = base + i;
        if (idx < n) {
            int4 a = ((const int4*)cnt8)[idx * 2];
            int4 b = ((const int4*)cnt8)[idx * 2 + 1];
            s += a.x + a.y + a.z + a.w + b.x + b.y + b.z + b.w;
        }
    }
    for (int d = 1; d < 64; d <<= 1) s += __shfl_xor(s, d, 64);
    __shared__ int ws[4];
    if ((threadIdx.x & 63) == 0) ws[threadIdx.x >> 6] = s;
    __syncthreads();
    if (threadIdx.x == 0) tsum[blockIdx.x] = ws[0] + ws[1] + ws[2] + ws[3];
}

// ---------------------------------------------------------------------------
// Scan stage 2: per-tile exclusive scan; tile base re-derived from tsum
// ---------------------------------------------------------------------------
__global__ __launch_bounds__(256) void scan_final(const int* __restrict__ cnt8,
                                                  const int* __restrict__ tsum,
                                                  int* __restrict__ offs, int n)
{
    const int lane = threadIdx.x & 63, wid = threadIdx.x >> 6;
    int tbase = 0;
    for (int i = 0; i < blockIdx.x; ++i) tbase += tsum[i];
    int base = blockIdx.x * SCAN_TILE + threadIdx.x * 16;
    int v[16]; int s = 0;
#pragma unroll
    for (int j = 0; j < 16; ++j) {
        int idx = base + j;
        int dv = 0;
        if (idx < n) {
            int4 a = ((const int4*)cnt8)[idx * 2];
            int4 b = ((const int4*)cnt8)[idx * 2 + 1];
            dv = a.x + a.y + a.z + a.w + b.x + b.y + b.z + b.w;
        }
        v[j] = dv; s += dv;
    }
    int inc = s;
    for (int d = 1; d < 64; d <<= 1) {
        int t = __shfl_up(inc, d, 64);
        if (lane >= d) inc += t;
    }
    __shared__ int wsum[4];
    if (lane == 63) wsum[wid] = inc;
    __syncthreads();
    int run = tbase + (inc - s);
    for (int k = 0; k < wid; ++k) run += wsum[k];
#pragma unroll
    for (int j = 0; j < 16; ++j) {
        int idx = base + j;
        if (idx < n) offs[idx] = run;
        run += v[j];
    }
}

// ---------------------------------------------------------------------------
// K5: scatter edges into dst-bucketed order; edgeP = {src*8+rel, bits(1/cnt)}
// (kept SEPARATE: fusing with gemm1 regressed — random 8B scatters contend
//  with streaming stores, +32MB write amplification in the same window)
// ---------------------------------------------------------------------------
__global__ __launch_bounds__(256) void scatter_kernel(const int* __restrict__ src,
                                                      const int* __restrict__ dst,
                                                      const int* __restrict__ et,
                                                      const int* __restrict__ offs,
                                                      int* __restrict__ cursor,
                                                      const int* __restrict__ cnt8,
                                                      int2* __restrict__ edgeP, int E)
{
    int e = blockIdx.x * 256 + threadIdx.x;
    if (e >= E) return;
    int d = dst[e], r = et[e], s = src[e];
    int c = cnt8[d * NREL + r];
    float inv = 1.0f / (float)(c > 1 ? c : 1);
    int pos = offs[d] + atomicAdd(&cursor[d], 1);
    edgeP[pos] = make_int2(s * NREL + r, __float_as_int(inv));
}

// ---------------------------------------------------------------------------
// Persistent fused all-relation + root GEMM: [N,K] x [K,576].
// Block (bx, by): col-tiles [by*12, by*12+12) staged to LDS ONCE, then loop
// over row-chunks. Grid.x sized so resident blocks = LDS capacity exactly.
// Epilogue (permuted slots c' = lr*4+tt, true ch = tt*16+lr):
//   rel groups -> hr[n][g*64+c'] bf16 int2; root group -> yb[n][c'] bf16 int2.
// ---------------------------------------------------------------------------
template<int K>
__global__ __launch_bounds__(256) void gemm_mfma(const short* __restrict__ xf,
                                                 const short* __restrict__ Wf,
                                                 const float* __restrict__ bias,
                                                 short* __restrict__ hr,
                                                 short* __restrict__ yb,
                                                 int N, int gblk)
{
    constexpr int NK = K / 32;
    __shared__ short lds[12 * NK * 512];

    const int w = threadIdx.x >> 6, lane = threadIdx.x & 63;
    const int kg = lane >> 4, lr = lane & 15;
    const int g0 = blockIdx.y * 3;

    {
        const int4* gsrc = (const int4*)(Wf + (size_t)g0 * 4 * NK * 512);
        int4* ldst = (int4*)lds;
        for (int i = threadIdx.x; i < 12 * NK * 64; i += 256)
            ldst[i] = gsrc[i];
    }

    float b0 = bias[lr], b1 = bias[16 + lr], b2 = bias[32 + lr], b3 = bias[48 + lr];

    __syncthreads();

    for (int bx = blockIdx.x; bx < gblk; bx += gridDim.x) {
        const int rt = bx * 4 + w;

        bf16x8 afrag[NK];
        const short* ap = xf + ((size_t)rt * NK * 64 + lane) * 8;
#pragma unroll
        for (int ks = 0; ks < NK; ++ks)
            afrag[ks] = *(const bf16x8*)(ap + ks * 512);

        f32x4 acc[12];
#pragma unroll
        for (int t = 0; t < 12; ++t) acc[t] = (f32x4){0.f, 0.f, 0.f, 0.f};

#pragma unroll
        for (int tt = 0; tt < 12; ++tt) {
#pragma unroll
            for (int ks = 0; ks < NK; ++ks) {
                bf16x8 bfrag = *(const bf16x8*)(lds + (tt * NK + ks) * 512 + lane * 8);
                acc[tt] = __builtin_amdgcn_mfma_f32_16x16x32_bf16(afrag[ks], bfrag,
                                                                  acc[tt], 0, 0, 0);
            }
        }

        const int drow0 = rt * 16 + kg * 4;
#pragma unroll
        for (int r = 0; r < 4; ++r) {
            int dr = drow0 + r;
            if (dr >= N) break;
#pragma unroll
            for (int gg = 0; gg < 3; ++gg) {
                int g = g0 + gg;
                if (g < 8) {
                    int u0 = pack2bf(acc[gg * 4 + 0][r], acc[gg * 4 + 1][r]);
                    int u1 = pack2bf(acc[gg * 4 + 2][r], acc[gg * 4 + 3][r]);
                    *(int2*)(hr + (size_t)dr * 512 + g * 64 + lr * 4) = make_int2(u0, u1);
                } else {
                    int u0 = pack2bf(acc[gg * 4 + 0][r] + b0, acc[gg * 4 + 1][r] + b1);
                    int u1 = pack2bf(acc[gg * 4 + 2][r] + b2, acc[gg * 4 + 3][r] + b3);
                    *(int2*)(yb + (size_t)dr * 64 + lr * 4) = make_int2(u0, u1);
                }
            }
        }
    }
}

// ---------------------------------------------------------------------------
// Aggregate: 2 waves per dst (even/odd edges), each 4-deep unrolled ->
// up to 8 outstanding gathers per dst. Block = 256 = 2 dst x 2 sub-waves.
// lane = permuted channel slot; per edge gather 128B contiguous.
// ---------------------------------------------------------------------------
template<bool BF16OUT>
__global__ __launch_bounds__(256) void agg_kernel(const int* __restrict__ offs,
                                                  const int2* __restrict__ edgeP,
                                                  const short* __restrict__ hr,
                                                  const short* __restrict__ yb,
                                                  float* __restrict__ outF,
                                                  short* __restrict__ outB, int N)
{
    __shared__ float red[2][64];
    const int w = threadIdx.x >> 6, l = threadIdx.x & 63;
    const int ds = w >> 1, sub = w & 1;
    const int dst = blockIdx.x * 2 + ds;

    const unsigned short* hp = (const unsigned short*)hr;
    float acc = 0.f;
    if (dst < N) {
        int e0 = offs[dst], e1 = offs[dst + 1];
        int e = e0 + sub;
        // 4-deep: edges e, e+2, e+4, e+6 (this sub-wave's stride-2 stream)
        for (; e + 6 < e1; e += 8) {
            int2 p0 = edgeP[e],     p1 = edgeP[e + 2];
            int2 p2 = edgeP[e + 4], p3 = edgeP[e + 6];
            unsigned short g0 = hp[(size_t)p0.x * 64 + l];
            unsigned short g1 = hp[(size_t)p1.x * 64 + l];
            unsigned short g2 = hp[(size_t)p2.x * 64 + l];
            unsigned short g3 = hp[(size_t)p3.x * 64 + l];
            acc = fmaf(bfval(g0), __int_as_float(p0.y), acc);
            acc = fmaf(bfval(g1), __int_as_float(p1.y), acc);
            acc = fmaf(bfval(g2), __int_as_float(p2.y), acc);
            acc = fmaf(bfval(g3), __int_as_float(p3.y), acc);
        }
        for (; e < e1; e += 2) {
            int2 p0 = edgeP[e];
            unsigned short g0 = hp[(size_t)p0.x * 64 + l];
            acc = fmaf(bfval(g0), __int_as_float(p0.y), acc);
        }
    }
    if (sub == 1) red[ds][l] = acc;
    __syncthreads();
    if (sub == 1 || dst >= N) return;

    acc += red[ds][l];
    acc += bfval(((const unsigned short*)yb)[(size_t)dst * 64 + l]);

    int tc = (l & 3) * 16 + (l >> 2);    // true channel
    if (BF16OUT) {
        // layer-2 A-fragment layout (K=64, NK=2), k = true channel
        int rt2 = dst >> 4, lr2 = dst & 15;
        int ks2 = tc >> 5, kg2 = (tc >> 3) & 3, e2 = tc & 7;
        outB[(((size_t)rt2 * 2 + ks2) * 64 + kg2 * 16 + lr2) * 8 + e2] =
            f2bf(fmaxf(acc, 0.f));
    } else {
        outF[(size_t)dst * 64 + tc] = acc;
    }
}

// ---------------------------------------------------------------------------
extern "C" void kernel_launch(void* const* d_in, const int* in_sizes, int n_in,
                              void* d_out, int out_size, void* d_ws, size_t ws_size,
                              hipStream_t stream)
{
    const float* x      = (const float*)d_in[0];
    const int*   ei     = (const int*)d_in[1];
    const int*   et     = (const int*)d_in[2];
    const float* basis1 = (const float*)d_in[3];
    const float* comp1  = (const float*)d_in[4];
    const float* root1  = (const float*)d_in[5];
    const float* bias1  = (const float*)d_in[6];
    const float* basis2 = (const float*)d_in[7];
    const float* comp2  = (const float*)d_in[8];
    const float* root2  = (const float*)d_in[9];
    const float* bias2  = (const float*)d_in[10];
    float* out = (float*)d_out;

    const int N = in_sizes[0] / 128;
    const int E = in_sizes[2];
    const int* src  = ei;
    const int* dstp = ei + E;

    const int gblk = (N + 63) / 64;
    const int NT   = gblk * 4;
    const int HB   = (E + 255) / 256;

    // -------- workspace carve (256B aligned) --------
    char* p = (char*)d_ws;
    auto carve = [&](size_t bytes) -> char* {
        char* q = p; p += (bytes + 255) & ~(size_t)255; return q;
    };
    int*   cursor  = (int*)carve((size_t)N * 4);          // zeroed
    int*   cnt8    = (int*)carve((size_t)N * NREL * 4);   // zeroed
    char*  zend    = p;
    int*   offs    = (int*)carve((size_t)(N + 1) * 4);
    int*   tsum    = (int*)carve(256 * 4);
    int2*  edgeP   = (int2*)carve((size_t)E * 8);
    short* Wf1     = (short*)carve((size_t)36 * 4 * 64 * 8 * 2);
    short* Wf2     = (short*)carve((size_t)36 * 2 * 64 * 8 * 2);
    short* yb      = (short*)carve((size_t)N * 64 * 2);
    short* xf1     = (short*)carve((size_t)NT * 4 * 64 * 8 * 2);
    short* xf2     = (short*)carve((size_t)NT * 2 * 64 * 8 * 2);
    short* hr      = (short*)carve((size_t)N * 512 * 2);

    const int zn16 = (int)((zend - (char*)cursor) / 16);
    const int ntiles = (N + SCAN_TILE - 1) / SCAN_TILE;

    // K1: zero + offs[N]=E
    zero_kernel<<<(zn16 + 255) / 256, 256, 0, stream>>>((int4*)cursor, zn16, offs + N, E);

    // K2: fused hist | wfrag1 | wfrag2 | afrag
    prep_hist_kernel<<<HB + 36 + 18 + NT, 256, 0, stream>>>(
        dstp, et, cnt8, basis1, root1, comp1, basis2, root2, comp2, x,
        Wf1, Wf2, xf1, E, N, NT, HB);

    // K3/K4: scan
    scan_part<<<ntiles, 256, 0, stream>>>(cnt8, tsum, N);
    scan_final<<<ntiles, 256, 0, stream>>>(cnt8, tsum, offs, N);

    // K5: scatter (separate — see comment)
    scatter_kernel<<<HB, 256, 0, stream>>>(src, dstp, et, offs, cursor,
                                           cnt8, edgeP, E);

    // K6: layer-1 GEMM (persistent; 768 blocks = 3/CU at 49KB LDS)
    gemm_mfma<128><<<dim3(256, 3), 256, 0, stream>>>(xf1, Wf1, bias1, hr, yb, N, gblk);

    // K7: layer-1 aggregate (writes relu result into layer-2 A-frag layout)
    agg_kernel<true><<<(N + 1) / 2, 256, 0, stream>>>(offs, edgeP, hr, yb,
                                                      nullptr, xf2, N);

    // K8: layer-2 GEMM (persistent; 1536 blocks = 6/CU at 24.6KB LDS)
    gemm_mfma<64><<<dim3(512, 3), 256, 0, stream>>>(xf2, Wf2, bias2, hr, yb, N, gblk);

    // K9: layer-2 aggregate -> d_out
    agg_kernel<false><<<(N + 1) / 2, 256, 0, stream>>>(offs, edgeP, hr, yb,
                                                       out, nullptr, N);
}

// Round 11
// 194.425 us; speedup vs baseline: 1.0732x; 1.0732x over previous
//
#include <hip/hip_runtime.h>
#include <cstddef>

#define NREL 8
#define SCAN_TILE 4096

typedef __bf16 bf16x8 __attribute__((ext_vector_type(8)));
typedef float f32x4 __attribute__((ext_vector_type(4)));
typedef unsigned short ushort_t;

__device__ __forceinline__ unsigned f2bf_u(float f) {
    unsigned u = __float_as_uint(f);
    u += 0x7FFFu + ((u >> 16) & 1u);           // RNE
    return u >> 16;
}
__device__ __forceinline__ short f2bf(float f) { return (short)f2bf_u(f); }
__device__ __forceinline__ int pack2bf(float lo, float hi) {
    return (int)(f2bf_u(lo) | (f2bf_u(hi) << 16));
}
__device__ __forceinline__ float bfval(unsigned short g) {
    return __uint_as_float((unsigned)g << 16);
}

// ---------------------------------------------------------------------------
// K1: zero cursor/cnt8/aggF1/aggF2 + offs[N] = E
// ---------------------------------------------------------------------------
__global__ __launch_bounds__(256) void zero_kernel(int4* __restrict__ p, int n16,
                                                   int* __restrict__ offsN, int E)
{
    int i = blockIdx.x * 256 + threadIdx.x;
    if (i < n16) p[i] = make_int4(0, 0, 0, 0);
    if (i == 0) *offsN = E;
}

// ---------------------------------------------------------------------------
// device bodies for fused prep
// ---------------------------------------------------------------------------
template<int K>
__device__ __forceinline__ void wfrag_body(const float* __restrict__ basis,
                                           const float* __restrict__ root,
                                           const float* __restrict__ comp,
                                           short* __restrict__ Wf, int tid)
{
    constexpr int NK = K / 32;
    int lane = tid & 63, slot = tid >> 6;
    int ks = slot % NK, t = slot / NK;
    int kg = lane >> 4, lr = lane & 15;
    int k0 = ks * 32 + kg * 8;
    union { short s[8]; int4 v; } u;
#pragma unroll
    for (int e = 0; e < 8; ++e) {
        int k = k0 + e;
        float v;
        if (t < 32) {
            int rr = t >> 2, ch = (t & 3) * 16 + lr;
            v = comp[rr * 4 + 0] * basis[((size_t)0 * K + k) * 64 + ch]
              + comp[rr * 4 + 1] * basis[((size_t)1 * K + k) * 64 + ch]
              + comp[rr * 4 + 2] * basis[((size_t)2 * K + k) * 64 + ch]
              + comp[rr * 4 + 3] * basis[((size_t)3 * K + k) * 64 + ch];
        } else {
            v = root[(size_t)k * 64 + (t - 32) * 16 + lr];
        }
        u.s[e] = f2bf(v);
    }
    *(int4*)(Wf + (size_t)tid * 8) = u.v;
}

__device__ __forceinline__ void afrag_body128(const float* __restrict__ x,
                                              short* __restrict__ xf, int N, int tid)
{
    int lane = tid & 63, slot = tid >> 6;
    int ks = slot & 3, rt = slot >> 2;
    int kg = lane >> 4, lr = lane & 15;
    int row = rt * 16 + lr, k = ks * 32 + kg * 8;
    union { short s[8]; int4 v; } u;
    if (row < N) {
        const float* xp = x + (size_t)row * 128 + k;
        float4 a = *(const float4*)xp;
        float4 b = *(const float4*)(xp + 4);
        u.s[0] = f2bf(a.x); u.s[1] = f2bf(a.y); u.s[2] = f2bf(a.z); u.s[3] = f2bf(a.w);
        u.s[4] = f2bf(b.x); u.s[5] = f2bf(b.y); u.s[6] = f2bf(b.z); u.s[7] = f2bf(b.w);
    } else {
        u.v = make_int4(0, 0, 0, 0);
    }
    *(int4*)(xf + (size_t)tid * 8) = u.v;
}

// ---------------------------------------------------------------------------
// K2: fused { hist | wfrag1 | wfrag2 | afrag(x) } — all independent
// ---------------------------------------------------------------------------
__global__ __launch_bounds__(256) void prep_hist_kernel(
    const int* __restrict__ dstp, const int* __restrict__ et, int* __restrict__ cnt8,
    const float* __restrict__ basis1, const float* __restrict__ root1,
    const float* __restrict__ comp1,  const float* __restrict__ basis2,
    const float* __restrict__ root2,  const float* __restrict__ comp2,
    const float* __restrict__ x,
    short* __restrict__ Wf1, short* __restrict__ Wf2, short* __restrict__ xf1,
    int E, int N, int NT, int HB)
{
    int b = blockIdx.x;
    if (b < HB) {
        int e = b * 256 + threadIdx.x;
        if (e < E) atomicAdd(&cnt8[dstp[e] * NREL + et[e]], 1);
        return;
    }
    b -= HB;
    if (b < 36) { wfrag_body<128>(basis1, root1, comp1, Wf1, b * 256 + threadIdx.x); return; }
    b -= 36;
    if (b < 18) { wfrag_body<64>(basis2, root2, comp2, Wf2, b * 256 + threadIdx.x); return; }
    b -= 18;
    int tid = b * 256 + threadIdx.x;
    if (tid < NT * 256) afrag_body128(x, xf1, N, tid);
}

// ---------------------------------------------------------------------------
// Scan stage 1: per-tile degree sums
// ---------------------------------------------------------------------------
__global__ __launch_bounds__(256) void scan_part(const int* __restrict__ cnt8,
                                                 int* __restrict__ tsum, int n)
{
    int base = blockIdx.x * SCAN_TILE;
    int s = 0;
    for (int i = threadIdx.x; i < SCAN_TILE; i += 256) {
        int idx = base + i;
        if (idx < n) {
            int4 a = ((const int4*)cnt8)[idx * 2];
            int4 b = ((const int4*)cnt8)[idx * 2 + 1];
            s += a.x + a.y + a.z + a.w + b.x + b.y + b.z + b.w;
        }
    }
    for (int d = 1; d < 64; d <<= 1) s += __shfl_xor(s, d, 64);
    __shared__ int ws[4];
    if ((threadIdx.x & 63) == 0) ws[threadIdx.x >> 6] = s;
    __syncthreads();
    if (threadIdx.x == 0) tsum[blockIdx.x] = ws[0] + ws[1] + ws[2] + ws[3];
}

// ---------------------------------------------------------------------------
// Scan stage 2: per-tile exclusive scan; tile base re-derived from tsum
// ---------------------------------------------------------------------------
__global__ __launch_bounds__(256) void scan_final(const int* __restrict__ cnt8,
                                                  const int* __restrict__ tsum,
                                                  int* __restrict__ offs, int n)
{
    const int lane = threadIdx.x & 63, wid = threadIdx.x >> 6;
    int tbase = 0;
    for (int i = 0; i < blockIdx.x; ++i) tbase += tsum[i];
    int base = blockIdx.x * SCAN_TILE + threadIdx.x * 16;
    int v[16]; int s = 0;
#pragma unroll
    for (int j = 0; j < 16; ++j) {
        int idx = base + j;
        int dv = 0;
        if (idx < n) {
            int4 a = ((const int4*)cnt8)[idx * 2];
            int4 b = ((const int4*)cnt8)[idx * 2 + 1];
            dv = a.x + a.y + a.z + a.w + b.x + b.y + b.z + b.w;
        }
        v[j] = dv; s += dv;
    }
    int inc = s;
    for (int d = 1; d < 64; d <<= 1) {
        int t = __shfl_up(inc, d, 64);
        if (lane >= d) inc += t;
    }
    __shared__ int wsum[4];
    if (lane == 63) wsum[wid] = inc;
    __syncthreads();
    int run = tbase + (inc - s);
    for (int k = 0; k < wid; ++k) run += wsum[k];
#pragma unroll
    for (int j = 0; j < 16; ++j) {
        int idx = base + j;
        if (idx < n) offs[idx] = run;
        run += v[j];
    }
}

// ---------------------------------------------------------------------------
// K5: scatter edges into dst-bucketed order.
// edgeP = {src*8+rel, bits(1/cnt)}; edgeD = dst (ushort, N < 65536)
// ---------------------------------------------------------------------------
__global__ __launch_bounds__(256) void scatter_kernel(const int* __restrict__ src,
                                                      const int* __restrict__ dst,
                                                      const int* __restrict__ et,
                                                      const int* __restrict__ offs,
                                                      int* __restrict__ cursor,
                                                      const int* __restrict__ cnt8,
                                                      int2* __restrict__ edgeP,
                                                      ushort_t* __restrict__ edgeD, int E)
{
    int e = blockIdx.x * 256 + threadIdx.x;
    if (e >= E) return;
    int d = dst[e], r = et[e], s = src[e];
    int c = cnt8[d * NREL + r];
    float inv = 1.0f / (float)(c > 1 ? c : 1);
    int pos = offs[d] + atomicAdd(&cursor[d], 1);
    edgeP[pos] = make_int2(s * NREL + r, __float_as_int(inv));
    edgeD[pos] = (ushort_t)d;
}

// ---------------------------------------------------------------------------
// Persistent fused all-relation + root GEMM: [N,K] x [K,576] (as round 10)
// ---------------------------------------------------------------------------
template<int K>
__global__ __launch_bounds__(256) void gemm_mfma(const short* __restrict__ xf,
                                                 const short* __restrict__ Wf,
                                                 const float* __restrict__ bias,
                                                 short* __restrict__ hr,
                                                 short* __restrict__ yb,
                                                 int N, int gblk)
{
    constexpr int NK = K / 32;
    __shared__ short lds[12 * NK * 512];

    const int w = threadIdx.x >> 6, lane = threadIdx.x & 63;
    const int kg = lane >> 4, lr = lane & 15;
    const int g0 = blockIdx.y * 3;

    {
        const int4* gsrc = (const int4*)(Wf + (size_t)g0 * 4 * NK * 512);
        int4* ldst = (int4*)lds;
        for (int i = threadIdx.x; i < 12 * NK * 64; i += 256)
            ldst[i] = gsrc[i];
    }

    float b0 = bias[lr], b1 = bias[16 + lr], b2 = bias[32 + lr], b3 = bias[48 + lr];

    __syncthreads();

    for (int bx = blockIdx.x; bx < gblk; bx += gridDim.x) {
        const int rt = bx * 4 + w;

        bf16x8 afrag[NK];
        const short* ap = xf + ((size_t)rt * NK * 64 + lane) * 8;
#pragma unroll
        for (int ks = 0; ks < NK; ++ks)
            afrag[ks] = *(const bf16x8*)(ap + ks * 512);

        f32x4 acc[12];
#pragma unroll
        for (int t = 0; t < 12; ++t) acc[t] = (f32x4){0.f, 0.f, 0.f, 0.f};

#pragma unroll
        for (int tt = 0; tt < 12; ++tt) {
#pragma unroll
            for (int ks = 0; ks < NK; ++ks) {
                bf16x8 bfrag = *(const bf16x8*)(lds + (tt * NK + ks) * 512 + lane * 8);
                acc[tt] = __builtin_amdgcn_mfma_f32_16x16x32_bf16(afrag[ks], bfrag,
                                                                  acc[tt], 0, 0, 0);
            }
        }

        const int drow0 = rt * 16 + kg * 4;
#pragma unroll
        for (int r = 0; r < 4; ++r) {
            int dr = drow0 + r;
            if (dr >= N) break;
#pragma unroll
            for (int gg = 0; gg < 3; ++gg) {
                int g = g0 + gg;
                if (g < 8) {
                    int u0 = pack2bf(acc[gg * 4 + 0][r], acc[gg * 4 + 1][r]);
                    int u1 = pack2bf(acc[gg * 4 + 2][r], acc[gg * 4 + 3][r]);
                    *(int2*)(hr + (size_t)dr * 512 + g * 64 + lr * 4) = make_int2(u0, u1);
                } else {
                    int u0 = pack2bf(acc[gg * 4 + 0][r] + b0, acc[gg * 4 + 1][r] + b1);
                    int u1 = pack2bf(acc[gg * 4 + 2][r] + b2, acc[gg * 4 + 3][r] + b3);
                    *(int2*)(yb + (size_t)dr * 64 + lr * 4) = make_int2(u0, u1);
                }
            }
        }
    }
}

// ---------------------------------------------------------------------------
// Edge-chunk aggregate: each wave owns 16 CONSECUTIVE bucketed edges
// (independent of dst boundaries). All 16 gathers issued up front -> 16
// outstanding 128B loads/wave. Wave-uniform segmented accumulate; each
// dst-run flushed via f32 HW atomics into zeroed aggF[N][64] (slot order).
// Flushes ~= #dsts + #chunk crossings (~81k) -> cheap fire-and-forget.
// ---------------------------------------------------------------------------
__global__ __launch_bounds__(256) void agg_chunk_kernel(
    const int2* __restrict__ edgeP, const ushort_t* __restrict__ edgeD,
    const short* __restrict__ hr, float* __restrict__ aggF, int E)
{
    const int w = threadIdx.x >> 6, l = threadIdx.x & 63;
    const int base = (blockIdx.x * 4 + w) * 16;
    if (base >= E) return;
    const int nv = min(16, E - base);

    // lane j (j = l & 15) holds edge base+j's metadata (dup'd across quads)
    int idx = base + (l & 15);
    if (idx >= E) idx = E - 1;
    int2 pl = edgeP[idx];
    int dl = (int)edgeD[idx];

    const unsigned short* hp = (const unsigned short*)hr;

    // issue all 16 gathers (uniform row per j, lane = channel slot)
    int g[16];
#pragma unroll
    for (int j = 0; j < 16; ++j) {
        int srj = __shfl(pl.x, j);
        g[j] = hp[(size_t)srj * 64 + l];
    }

    // wave-uniform segmented accumulate + atomic flush per dst-run
    float acc = 0.f;
#pragma unroll
    for (int j = 0; j < 16; ++j) {
        if (j >= nv) break;
        float invj = __uint_as_float(__shfl(pl.y, j));
        acc = fmaf(bfval((unsigned short)g[j]), invj, acc);
        int dcur = __shfl(dl, j);
        int dnxt = __shfl(dl, (j + 1) & 15);
        if (j == nv - 1 || dnxt != dcur) {
            unsafeAtomicAdd(&aggF[(size_t)dcur * 64 + l], acc);
            acc = 0.f;
        }
    }
}

// ---------------------------------------------------------------------------
// Aggregate finish: v = aggF + yb(root+bias). Layer 1: relu -> bf16 xf2 frag;
// layer 2: f32 -> d_out in true-channel order.
// ---------------------------------------------------------------------------
template<bool BF16OUT>
__global__ __launch_bounds__(256) void agg_fin_kernel(const float* __restrict__ aggF,
                                                      const short* __restrict__ yb,
                                                      float* __restrict__ outF,
                                                      short* __restrict__ outB, int N)
{
    int i = blockIdx.x * 256 + threadIdx.x;
    if (i >= N * 64) return;
    int dst = i >> 6, l = i & 63;
    float v = aggF[i] + bfval(((const ushort_t*)yb)[i]);
    int tc = (l & 3) * 16 + (l >> 2);    // true channel
    if (BF16OUT) {
        int rt2 = dst >> 4, lr2 = dst & 15;
        int ks2 = tc >> 5, kg2 = (tc >> 3) & 3, e2 = tc & 7;
        outB[(((size_t)rt2 * 2 + ks2) * 64 + kg2 * 16 + lr2) * 8 + e2] =
            f2bf(fmaxf(v, 0.f));
    } else {
        outF[(size_t)dst * 64 + tc] = v;
    }
}

// ---------------------------------------------------------------------------
extern "C" void kernel_launch(void* const* d_in, const int* in_sizes, int n_in,
                              void* d_out, int out_size, void* d_ws, size_t ws_size,
                              hipStream_t stream)
{
    const float* x      = (const float*)d_in[0];
    const int*   ei     = (const int*)d_in[1];
    const int*   et     = (const int*)d_in[2];
    const float* basis1 = (const float*)d_in[3];
    const float* comp1  = (const float*)d_in[4];
    const float* root1  = (const float*)d_in[5];
    const float* bias1  = (const float*)d_in[6];
    const float* basis2 = (const float*)d_in[7];
    const float* comp2  = (const float*)d_in[8];
    const float* root2  = (const float*)d_in[9];
    const float* bias2  = (const float*)d_in[10];
    float* out = (float*)d_out;

    const int N = in_sizes[0] / 128;
    const int E = in_sizes[2];
    const int* src  = ei;
    const int* dstp = ei + E;

    const int gblk = (N + 63) / 64;
    const int NT   = gblk * 4;
    const int HB   = (E + 255) / 256;

    // -------- workspace carve (256B aligned) --------
    char* p = (char*)d_ws;
    auto carve = [&](size_t bytes) -> char* {
        char* q = p; p += (bytes + 255) & ~(size_t)255; return q;
    };
    int*   cursor  = (int*)carve((size_t)N * 4);            // zeroed
    int*   cnt8    = (int*)carve((size_t)N * NREL * 4);     // zeroed
    float* aggF1   = (float*)carve((size_t)N * 64 * 4);     // zeroed
    float* aggF2   = (float*)carve((size_t)N * 64 * 4);     // zeroed
    char*  zend    = p;
    int*   offs    = (int*)carve((size_t)(N + 1) * 4);
    int*   tsum    = (int*)carve(256 * 4);
    int2*  edgeP   = (int2*)carve((size_t)E * 8);
    ushort_t* edgeD = (ushort_t*)carve((size_t)E * 2);
    short* Wf1     = (short*)carve((size_t)36 * 4 * 64 * 8 * 2);
    short* Wf2     = (short*)carve((size_t)36 * 2 * 64 * 8 * 2);
    short* yb      = (short*)carve((size_t)N * 64 * 2);
    short* xf1     = (short*)carve((size_t)NT * 4 * 64 * 8 * 2);
    short* xf2     = (short*)carve((size_t)NT * 2 * 64 * 8 * 2);
    short* hr      = (short*)carve((size_t)N * 512 * 2);

    const int zn16 = (int)((zend - (char*)cursor) / 16);
    const int ntiles = (N + SCAN_TILE - 1) / SCAN_TILE;
    const int CHB = (E + 63) / 64;      // agg chunk blocks (4 waves x 16 edges)
    const int FB  = (N * 64 + 255) / 256;

    // K1: zero (cursor, cnt8, aggF1, aggF2) + offs[N]=E
    zero_kernel<<<(zn16 + 255) / 256, 256, 0, stream>>>((int4*)cursor, zn16, offs + N, E);

    // K2: fused hist | wfrag1 | wfrag2 | afrag
    prep_hist_kernel<<<HB + 36 + 18 + NT, 256, 0, stream>>>(
        dstp, et, cnt8, basis1, root1, comp1, basis2, root2, comp2, x,
        Wf1, Wf2, xf1, E, N, NT, HB);

    // K3/K4: scan
    scan_part<<<ntiles, 256, 0, stream>>>(cnt8, tsum, N);
    scan_final<<<ntiles, 256, 0, stream>>>(cnt8, tsum, offs, N);

    // K5: scatter
    scatter_kernel<<<HB, 256, 0, stream>>>(src, dstp, et, offs, cursor,
                                           cnt8, edgeP, edgeD, E);

    // ---- layer 1 ----
    gemm_mfma<128><<<dim3(256, 3), 256, 0, stream>>>(xf1, Wf1, bias1, hr, yb, N, gblk);
    agg_chunk_kernel<<<CHB, 256, 0, stream>>>(edgeP, edgeD, hr, aggF1, E);
    agg_fin_kernel<true><<<FB, 256, 0, stream>>>(aggF1, yb, nullptr, xf2, N);

    // ---- layer 2 ----
    gemm_mfma<64><<<dim3(512, 3), 256, 0, stream>>>(xf2, Wf2, bias2, hr, yb, N, gblk);
    agg_chunk_kernel<<<CHB, 256, 0, stream>>>(edgeP, edgeD, hr, aggF2, E);
    agg_fin_kernel<false><<<FB, 256, 0, stream>>>(aggF2, yb, out, nullptr, N);
}

// Round 12
// 177.118 us; speedup vs baseline: 1.1781x; 1.0977x over previous
//
#include <hip/hip_runtime.h>
#include <cstddef>

#define NREL 8
#define SCAN_TILE 4096

typedef __bf16 bf16x8 __attribute__((ext_vector_type(8)));
typedef float f32x4 __attribute__((ext_vector_type(4)));
typedef unsigned short ushort_t;

__device__ __forceinline__ unsigned f2bf_u(float f) {
    unsigned u = __float_as_uint(f);
    u += 0x7FFFu + ((u >> 16) & 1u);           // RNE
    return u >> 16;
}
__device__ __forceinline__ short f2bf(float f) { return (short)f2bf_u(f); }
__device__ __forceinline__ int pack2bf(float lo, float hi) {
    return (int)(f2bf_u(lo) | (f2bf_u(hi) << 16));
}
__device__ __forceinline__ float bfval(unsigned short g) {
    return __uint_as_float((unsigned)g << 16);
}

// ---------------------------------------------------------------------------
// K1: zero cursor/cnt8/aggF1/aggF2 + offs[N] = E
// ---------------------------------------------------------------------------
__global__ __launch_bounds__(256) void zero_kernel(int4* __restrict__ p, int n16,
                                                   int* __restrict__ offsN, int E)
{
    int i = blockIdx.x * 256 + threadIdx.x;
    if (i < n16) p[i] = make_int4(0, 0, 0, 0);
    if (i == 0) *offsN = E;
}

// ---------------------------------------------------------------------------
// device bodies for fused prep
// ---------------------------------------------------------------------------
template<int K>
__device__ __forceinline__ void wfrag_body(const float* __restrict__ basis,
                                           const float* __restrict__ root,
                                           const float* __restrict__ comp,
                                           short* __restrict__ Wf, int tid)
{
    constexpr int NK = K / 32;
    int lane = tid & 63, slot = tid >> 6;
    int ks = slot % NK, t = slot / NK;
    int kg = lane >> 4, lr = lane & 15;
    int k0 = ks * 32 + kg * 8;
    union { short s[8]; int4 v; } u;
#pragma unroll
    for (int e = 0; e < 8; ++e) {
        int k = k0 + e;
        float v;
        if (t < 32) {
            int rr = t >> 2, ch = (t & 3) * 16 + lr;
            v = comp[rr * 4 + 0] * basis[((size_t)0 * K + k) * 64 + ch]
              + comp[rr * 4 + 1] * basis[((size_t)1 * K + k) * 64 + ch]
              + comp[rr * 4 + 2] * basis[((size_t)2 * K + k) * 64 + ch]
              + comp[rr * 4 + 3] * basis[((size_t)3 * K + k) * 64 + ch];
        } else {
            v = root[(size_t)k * 64 + (t - 32) * 16 + lr];
        }
        u.s[e] = f2bf(v);
    }
    *(int4*)(Wf + (size_t)tid * 8) = u.v;
}

__device__ __forceinline__ void afrag_body128(const float* __restrict__ x,
                                              short* __restrict__ xf, int N, int tid)
{
    int lane = tid & 63, slot = tid >> 6;
    int ks = slot & 3, rt = slot >> 2;
    int kg = lane >> 4, lr = lane & 15;
    int row = rt * 16 + lr, k = ks * 32 + kg * 8;
    union { short s[8]; int4 v; } u;
    if (row < N) {
        const float* xp = x + (size_t)row * 128 + k;
        float4 a = *(const float4*)xp;
        float4 b = *(const float4*)(xp + 4);
        u.s[0] = f2bf(a.x); u.s[1] = f2bf(a.y); u.s[2] = f2bf(a.z); u.s[3] = f2bf(a.w);
        u.s[4] = f2bf(b.x); u.s[5] = f2bf(b.y); u.s[6] = f2bf(b.z); u.s[7] = f2bf(b.w);
    } else {
        u.v = make_int4(0, 0, 0, 0);
    }
    *(int4*)(xf + (size_t)tid * 8) = u.v;
}

// ---------------------------------------------------------------------------
// K2: fused { hist | wfrag1 | wfrag2 | afrag(x) } — all independent
// ---------------------------------------------------------------------------
__global__ __launch_bounds__(256) void prep_hist_kernel(
    const int* __restrict__ dstp, const int* __restrict__ et, int* __restrict__ cnt8,
    const float* __restrict__ basis1, const float* __restrict__ root1,
    const float* __restrict__ comp1,  const float* __restrict__ basis2,
    const float* __restrict__ root2,  const float* __restrict__ comp2,
    const float* __restrict__ x,
    short* __restrict__ Wf1, short* __restrict__ Wf2, short* __restrict__ xf1,
    int E, int N, int NT, int HB)
{
    int b = blockIdx.x;
    if (b < HB) {
        int e = b * 256 + threadIdx.x;
        if (e < E) atomicAdd(&cnt8[dstp[e] * NREL + et[e]], 1);
        return;
    }
    b -= HB;
    if (b < 36) { wfrag_body<128>(basis1, root1, comp1, Wf1, b * 256 + threadIdx.x); return; }
    b -= 36;
    if (b < 18) { wfrag_body<64>(basis2, root2, comp2, Wf2, b * 256 + threadIdx.x); return; }
    b -= 18;
    int tid = b * 256 + threadIdx.x;
    if (tid < NT * 256) afrag_body128(x, xf1, N, tid);
}

// ---------------------------------------------------------------------------
// Scan stage 1: per-tile degree sums
// ---------------------------------------------------------------------------
__global__ __launch_bounds__(256) void scan_part(const int* __restrict__ cnt8,
                                                 int* __restrict__ tsum, int n)
{
    int base = blockIdx.x * SCAN_TILE;
    int s = 0;
    for (int i = threadIdx.x; i < SCAN_TILE; i += 256) {
        int idx = base + i;
        if (idx < n) {
            int4 a = ((const int4*)cnt8)[idx * 2];
            int4 b = ((const int4*)cnt8)[idx * 2 + 1];
            s += a.x + a.y + a.z + a.w + b.x + b.y + b.z + b.w;
        }
    }
    for (int d = 1; d < 64; d <<= 1) s += __shfl_xor(s, d, 64);
    __shared__ int ws[4];
    if ((threadIdx.x & 63) == 0) ws[threadIdx.x >> 6] = s;
    __syncthreads();
    if (threadIdx.x == 0) tsum[blockIdx.x] = ws[0] + ws[1] + ws[2] + ws[3];
}

// ---------------------------------------------------------------------------
// Scan stage 2: per-tile exclusive scan; tile base re-derived from tsum
// ---------------------------------------------------------------------------
__global__ __launch_bounds__(256) void scan_final(const int* __restrict__ cnt8,
                                                  const int* __restrict__ tsum,
                                                  int* __restrict__ offs, int n)
{
    const int lane = threadIdx.x & 63, wid = threadIdx.x >> 6;
    int tbase = 0;
    for (int i = 0; i < blockIdx.x; ++i) tbase += tsum[i];
    int base = blockIdx.x * SCAN_TILE + threadIdx.x * 16;
    int v[16]; int s = 0;
#pragma unroll
    for (int j = 0; j < 16; ++j) {
        int idx = base + j;
        int dv = 0;
        if (idx < n) {
            int4 a = ((const int4*)cnt8)[idx * 2];
            int4 b = ((const int4*)cnt8)[idx * 2 + 1];
            dv = a.x + a.y + a.z + a.w + b.x + b.y + b.z + b.w;
        }
        v[j] = dv; s += dv;
    }
    int inc = s;
    for (int d = 1; d < 64; d <<= 1) {
        int t = __shfl_up(inc, d, 64);
        if (lane >= d) inc += t;
    }
    __shared__ int wsum[4];
    if (lane == 63) wsum[wid] = inc;
    __syncthreads();
    int run = tbase + (inc - s);
    for (int k = 0; k < wid; ++k) run += wsum[k];
#pragma unroll
    for (int j = 0; j < 16; ++j) {
        int idx = base + j;
        if (idx < n) offs[idx] = run;
        run += v[j];
    }
}

// ---------------------------------------------------------------------------
// K5: scatter edges into dst-bucketed order.
// edgeP = int4 { (src*8+rel)*64, bits(1/cnt), dst, 0 } — one 16B scatter
// ---------------------------------------------------------------------------
__global__ __launch_bounds__(256) void scatter_kernel(const int* __restrict__ src,
                                                      const int* __restrict__ dst,
                                                      const int* __restrict__ et,
                                                      const int* __restrict__ offs,
                                                      int* __restrict__ cursor,
                                                      const int* __restrict__ cnt8,
                                                      int4* __restrict__ edgeP, int E)
{
    int e = blockIdx.x * 256 + threadIdx.x;
    if (e >= E) return;
    int d = dst[e], r = et[e], s = src[e];
    int c = cnt8[d * NREL + r];
    float inv = 1.0f / (float)(c > 1 ? c : 1);
    int pos = offs[d] + atomicAdd(&cursor[d], 1);
    edgeP[pos] = make_int4((s * NREL + r) * 64, __float_as_int(inv), d, 0);
}

// ---------------------------------------------------------------------------
// Persistent fused all-relation + root GEMM: [N,K] x [K,576], 9-way col split.
// Block (bx, by): ONE 4-tile col group by (rel by<8, root by==8), LDS-staged
// once; persistent loop over row-chunks. acc[4] -> ~60 VGPR -> ~32 waves/CU
// for store-drain overlap (the round-8..11 gemms were store-drain bound at
// ~12 waves/CU). Group g writes bytes [g*128, g*128+128) of each 1KB hr row
// (no false sharing between blocks).
// ---------------------------------------------------------------------------
template<int K>
__global__ __launch_bounds__(256) void gemm_mfma(const short* __restrict__ xf,
                                                 const short* __restrict__ Wf,
                                                 const float* __restrict__ bias,
                                                 short* __restrict__ hr,
                                                 short* __restrict__ yb,
                                                 int N, int gblk)
{
    constexpr int NK = K / 32;
    __shared__ short lds[4 * NK * 512];

    const int w = threadIdx.x >> 6, lane = threadIdx.x & 63;
    const int kg = lane >> 4, lr = lane & 15;
    const int g = blockIdx.y;   // 0..7 = rel, 8 = root

    {
        const int4* gsrc = (const int4*)(Wf + (size_t)g * 4 * NK * 512);
        int4* ldst = (int4*)lds;
        for (int i = threadIdx.x; i < 4 * NK * 64; i += 256)
            ldst[i] = gsrc[i];
    }

    float b0 = bias[lr], b1 = bias[16 + lr], b2 = bias[32 + lr], b3 = bias[48 + lr];

    __syncthreads();

    for (int bx = blockIdx.x; bx < gblk; bx += gridDim.x) {
        const int rt = bx * 4 + w;

        bf16x8 afrag[NK];
        const short* ap = xf + ((size_t)rt * NK * 64 + lane) * 8;
#pragma unroll
        for (int ks = 0; ks < NK; ++ks)
            afrag[ks] = *(const bf16x8*)(ap + ks * 512);

        f32x4 acc[4];
#pragma unroll
        for (int t = 0; t < 4; ++t) acc[t] = (f32x4){0.f, 0.f, 0.f, 0.f};

#pragma unroll
        for (int tt = 0; tt < 4; ++tt) {
#pragma unroll
            for (int ks = 0; ks < NK; ++ks) {
                bf16x8 bfrag = *(const bf16x8*)(lds + (tt * NK + ks) * 512 + lane * 8);
                acc[tt] = __builtin_amdgcn_mfma_f32_16x16x32_bf16(afrag[ks], bfrag,
                                                                  acc[tt], 0, 0, 0);
            }
        }

        const int drow0 = rt * 16 + kg * 4;
#pragma unroll
        for (int r = 0; r < 4; ++r) {
            int dr = drow0 + r;
            if (dr >= N) break;
            if (g < 8) {
                int u0 = pack2bf(acc[0][r], acc[1][r]);
                int u1 = pack2bf(acc[2][r], acc[3][r]);
                *(int2*)(hr + (size_t)dr * 512 + g * 64 + lr * 4) = make_int2(u0, u1);
            } else {
                int u0 = pack2bf(acc[0][r] + b0, acc[1][r] + b1);
                int u1 = pack2bf(acc[2][r] + b2, acc[3][r] + b3);
                *(int2*)(yb + (size_t)dr * 64 + lr * 4) = make_int2(u0, u1);
            }
        }
    }
}

// ---------------------------------------------------------------------------
// Edge-chunk aggregate: each wave owns 32 CONSECUTIVE bucketed edges.
// All 32 gathers issued up front -> 32 outstanding 128B loads/wave.
// Wave-uniform segmented accumulate; dst-runs flushed via f32 HW atomics
// into zeroed aggF[N][64] (slot order).
// ---------------------------------------------------------------------------
__global__ __launch_bounds__(256) void agg_chunk_kernel(
    const int4* __restrict__ edgeP, const short* __restrict__ hr,
    float* __restrict__ aggF, int E)
{
    const int w = threadIdx.x >> 6, l = threadIdx.x & 63;
    const int base = (blockIdx.x * 4 + w) * 32;
    if (base >= E) return;
    const int nv = min(32, E - base);

    // lane j (j = l & 31) holds edge base+j's metadata (dup'd across halves)
    int idx = base + (l & 31);
    if (idx >= E) idx = E - 1;
    int4 pl = edgeP[idx];

    const unsigned short* hp = (const unsigned short*)hr;

    // issue all 32 gathers (uniform row per j, lane = channel slot)
    int g[32];
#pragma unroll
    for (int j = 0; j < 32; ++j) {
        int hoff = __shfl(pl.x, j);
        g[j] = hp[(size_t)hoff + l];
    }

    // wave-uniform segmented accumulate + atomic flush per dst-run
    float acc = 0.f;
#pragma unroll
    for (int j = 0; j < 32; ++j) {
        if (j >= nv) break;
        float invj = __uint_as_float(__shfl(pl.y, j));
        acc = fmaf(bfval((unsigned short)g[j]), invj, acc);
        int dcur = __shfl(pl.z, j);
        int dnxt = __shfl(pl.z, (j + 1) & 31);
        if (j == nv - 1 || dnxt != dcur) {
            unsafeAtomicAdd(&aggF[(size_t)dcur * 64 + l], acc);
            acc = 0.f;
        }
    }
}

// ---------------------------------------------------------------------------
// Aggregate finish: v = aggF + yb(root+bias). Layer 1: relu -> bf16 xf2 frag;
// layer 2: f32 -> d_out in true-channel order.
// ---------------------------------------------------------------------------
template<bool BF16OUT>
__global__ __launch_bounds__(256) void agg_fin_kernel(const float* __restrict__ aggF,
                                                      const short* __restrict__ yb,
                                                      float* __restrict__ outF,
                                                      short* __restrict__ outB, int N)
{
    int i = blockIdx.x * 256 + threadIdx.x;
    if (i >= N * 64) return;
    int dst = i >> 6, l = i & 63;
    float v = aggF[i] + bfval(((const ushort_t*)yb)[i]);
    int tc = (l & 3) * 16 + (l >> 2);    // true channel
    if (BF16OUT) {
        int rt2 = dst >> 4, lr2 = dst & 15;
        int ks2 = tc >> 5, kg2 = (tc >> 3) & 3, e2 = tc & 7;
        outB[(((size_t)rt2 * 2 + ks2) * 64 + kg2 * 16 + lr2) * 8 + e2] =
            f2bf(fmaxf(v, 0.f));
    } else {
        outF[(size_t)dst * 64 + tc] = v;
    }
}

// ---------------------------------------------------------------------------
extern "C" void kernel_launch(void* const* d_in, const int* in_sizes, int n_in,
                              void* d_out, int out_size, void* d_ws, size_t ws_size,
                              hipStream_t stream)
{
    const float* x      = (const float*)d_in[0];
    const int*   ei     = (const int*)d_in[1];
    const int*   et     = (const int*)d_in[2];
    const float* basis1 = (const float*)d_in[3];
    const float* comp1  = (const float*)d_in[4];
    const float* root1  = (const float*)d_in[5];
    const float* bias1  = (const float*)d_in[6];
    const float* basis2 = (const float*)d_in[7];
    const float* comp2  = (const float*)d_in[8];
    const float* root2  = (const float*)d_in[9];
    const float* bias2  = (const float*)d_in[10];
    float* out = (float*)d_out;

    const int N = in_sizes[0] / 128;
    const int E = in_sizes[2];
    const int* src  = ei;
    const int* dstp = ei + E;

    const int gblk = (N + 63) / 64;
    const int NT   = gblk * 4;
    const int HB   = (E + 255) / 256;

    // -------- workspace carve (256B aligned) --------
    char* p = (char*)d_ws;
    auto carve = [&](size_t bytes) -> char* {
        char* q = p; p += (bytes + 255) & ~(size_t)255; return q;
    };
    int*   cursor  = (int*)carve((size_t)N * 4);            // zeroed
    int*   cnt8    = (int*)carve((size_t)N * NREL * 4);     // zeroed
    float* aggF1   = (float*)carve((size_t)N * 64 * 4);     // zeroed
    float* aggF2   = (float*)carve((size_t)N * 64 * 4);     // zeroed
    char*  zend    = p;
    int*   offs    = (int*)carve((size_t)(N + 1) * 4);
    int*   tsum    = (int*)carve(256 * 4);
    int4*  edgeP   = (int4*)carve((size_t)E * 16);
    short* Wf1     = (short*)carve((size_t)36 * 4 * 64 * 8 * 2);
    short* Wf2     = (short*)carve((size_t)36 * 2 * 64 * 8 * 2);
    short* yb      = (short*)carve((size_t)N * 64 * 2);
    short* xf1     = (short*)carve((size_t)NT * 4 * 64 * 8 * 2);
    short* xf2     = (short*)carve((size_t)NT * 2 * 64 * 8 * 2);
    short* hr      = (short*)carve((size_t)N * 512 * 2);

    const int zn16 = (int)((zend - (char*)cursor) / 16);
    const int ntiles = (N + SCAN_TILE - 1) / SCAN_TILE;
    const int CHB = (E + 127) / 128;    // agg chunk blocks (4 waves x 32 edges)
    const int FB  = (N * 64 + 255) / 256;

    // K1: zero (cursor, cnt8, aggF1, aggF2) + offs[N]=E
    zero_kernel<<<(zn16 + 255) / 256, 256, 0, stream>>>((int4*)cursor, zn16, offs + N, E);

    // K2: fused hist | wfrag1 | wfrag2 | afrag
    prep_hist_kernel<<<HB + 36 + 18 + NT, 256, 0, stream>>>(
        dstp, et, cnt8, basis1, root1, comp1, basis2, root2, comp2, x,
        Wf1, Wf2, xf1, E, N, NT, HB);

    // K3/K4: scan
    scan_part<<<ntiles, 256, 0, stream>>>(cnt8, tsum, N);
    scan_final<<<ntiles, 256, 0, stream>>>(cnt8, tsum, offs, N);

    // K5: scatter
    scatter_kernel<<<HB, 256, 0, stream>>>(src, dstp, et, offs, cursor,
                                           cnt8, edgeP, E);

    // ---- layer 1 ----
    gemm_mfma<128><<<dim3(256, 9), 256, 0, stream>>>(xf1, Wf1, bias1, hr, yb, N, gblk);
    agg_chunk_kernel<<<CHB, 256, 0, stream>>>(edgeP, hr, aggF1, E);
    agg_fin_kernel<true><<<FB, 256, 0, stream>>>(aggF1, yb, nullptr, xf2, N);

    // ---- layer 2 ----
    gemm_mfma<64><<<dim3(256, 9), 256, 0, stream>>>(xf2, Wf2, bias2, hr, yb, N, gblk);
    agg_chunk_kernel<<<CHB, 256, 0, stream>>>(edgeP, hr, aggF2, E);
    agg_fin_kernel<false><<<FB, 256, 0, stream>>>(aggF2, yb, out, nullptr, N);
}

// Round 13
// 165.405 us; speedup vs baseline: 1.2615x; 1.0708x over previous
//
#include <hip/hip_runtime.h>
#include <cstddef>

#define NREL 8
#define SCAN_TILE 4096

typedef __bf16 bf16x8 __attribute__((ext_vector_type(8)));
typedef float f32x4 __attribute__((ext_vector_type(4)));
typedef unsigned short ushort_t;

__device__ __forceinline__ unsigned f2bf_u(float f) {
    unsigned u = __float_as_uint(f);
    u += 0x7FFFu + ((u >> 16) & 1u);           // RNE
    return u >> 16;
}
__device__ __forceinline__ short f2bf(float f) { return (short)f2bf_u(f); }
__device__ __forceinline__ int pack2bf(float lo, float hi) {
    return (int)(f2bf_u(lo) | (f2bf_u(hi) << 16));
}
__device__ __forceinline__ float bfval(unsigned short g) {
    return __uint_as_float((unsigned)g << 16);
}

// ---------------------------------------------------------------------------
// K1: zero cursor/cnt8 + offs[N] = E (aggF/d_out now initialized by gemms)
// ---------------------------------------------------------------------------
__global__ __launch_bounds__(256) void zero_kernel(int4* __restrict__ p, int n16,
                                                   int* __restrict__ offsN, int E)
{
    int i = blockIdx.x * 256 + threadIdx.x;
    if (i < n16) p[i] = make_int4(0, 0, 0, 0);
    if (i == 0) *offsN = E;
}

// ---------------------------------------------------------------------------
// device bodies for fused prep
// ---------------------------------------------------------------------------
template<int K>
__device__ __forceinline__ void wfrag_body(const float* __restrict__ basis,
                                           const float* __restrict__ root,
                                           const float* __restrict__ comp,
                                           short* __restrict__ Wf, int tid)
{
    constexpr int NK = K / 32;
    int lane = tid & 63, slot = tid >> 6;
    int ks = slot % NK, t = slot / NK;
    int kg = lane >> 4, lr = lane & 15;
    int k0 = ks * 32 + kg * 8;
    union { short s[8]; int4 v; } u;
#pragma unroll
    for (int e = 0; e < 8; ++e) {
        int k = k0 + e;
        float v;
        if (t < 32) {
            int rr = t >> 2, ch = (t & 3) * 16 + lr;
            v = comp[rr * 4 + 0] * basis[((size_t)0 * K + k) * 64 + ch]
              + comp[rr * 4 + 1] * basis[((size_t)1 * K + k) * 64 + ch]
              + comp[rr * 4 + 2] * basis[((size_t)2 * K + k) * 64 + ch]
              + comp[rr * 4 + 3] * basis[((size_t)3 * K + k) * 64 + ch];
        } else {
            v = root[(size_t)k * 64 + (t - 32) * 16 + lr];
        }
        u.s[e] = f2bf(v);
    }
    *(int4*)(Wf + (size_t)tid * 8) = u.v;
}

__device__ __forceinline__ void afrag_body128(const float* __restrict__ x,
                                              short* __restrict__ xf, int N, int tid)
{
    int lane = tid & 63, slot = tid >> 6;
    int ks = slot & 3, rt = slot >> 2;
    int kg = lane >> 4, lr = lane & 15;
    int row = rt * 16 + lr, k = ks * 32 + kg * 8;
    union { short s[8]; int4 v; } u;
    if (row < N) {
        const float* xp = x + (size_t)row * 128 + k;
        float4 a = *(const float4*)xp;
        float4 b = *(const float4*)(xp + 4);
        u.s[0] = f2bf(a.x); u.s[1] = f2bf(a.y); u.s[2] = f2bf(a.z); u.s[3] = f2bf(a.w);
        u.s[4] = f2bf(b.x); u.s[5] = f2bf(b.y); u.s[6] = f2bf(b.z); u.s[7] = f2bf(b.w);
    } else {
        u.v = make_int4(0, 0, 0, 0);
    }
    *(int4*)(xf + (size_t)tid * 8) = u.v;
}

// ---------------------------------------------------------------------------
// K2: fused { hist | wfrag1 | wfrag2 | afrag(x) } — all independent
// ---------------------------------------------------------------------------
__global__ __launch_bounds__(256) void prep_hist_kernel(
    const int* __restrict__ dstp, const int* __restrict__ et, int* __restrict__ cnt8,
    const float* __restrict__ basis1, const float* __restrict__ root1,
    const float* __restrict__ comp1,  const float* __restrict__ basis2,
    const float* __restrict__ root2,  const float* __restrict__ comp2,
    const float* __restrict__ x,
    short* __restrict__ Wf1, short* __restrict__ Wf2, short* __restrict__ xf1,
    int E, int N, int NT, int HB)
{
    int b = blockIdx.x;
    if (b < HB) {
        int e = b * 256 + threadIdx.x;
        if (e < E) atomicAdd(&cnt8[dstp[e] * NREL + et[e]], 1);
        return;
    }
    b -= HB;
    if (b < 36) { wfrag_body<128>(basis1, root1, comp1, Wf1, b * 256 + threadIdx.x); return; }
    b -= 36;
    if (b < 18) { wfrag_body<64>(basis2, root2, comp2, Wf2, b * 256 + threadIdx.x); return; }
    b -= 18;
    int tid = b * 256 + threadIdx.x;
    if (tid < NT * 256) afrag_body128(x, xf1, N, tid);
}

// ---------------------------------------------------------------------------
// Scan stage 1: per-tile degree sums
// ---------------------------------------------------------------------------
__global__ __launch_bounds__(256) void scan_part(const int* __restrict__ cnt8,
                                                 int* __restrict__ tsum, int n)
{
    int base = blockIdx.x * SCAN_TILE;
    int s = 0;
    for (int i = threadIdx.x; i < SCAN_TILE; i += 256) {
        int idx = base + i;
        if (idx < n) {
            int4 a = ((const int4*)cnt8)[idx * 2];
            int4 b = ((const int4*)cnt8)[idx * 2 + 1];
            s += a.x + a.y + a.z + a.w + b.x + b.y + b.z + b.w;
        }
    }
    for (int d = 1; d < 64; d <<= 1) s += __shfl_xor(s, d, 64);
    __shared__ int ws[4];
    if ((threadIdx.x & 63) == 0) ws[threadIdx.x >> 6] = s;
    __syncthreads();
    if (threadIdx.x == 0) tsum[blockIdx.x] = ws[0] + ws[1] + ws[2] + ws[3];
}

// ---------------------------------------------------------------------------
// Scan stage 2: per-tile exclusive scan; tile base re-derived from tsum
// ---------------------------------------------------------------------------
__global__ __launch_bounds__(256) void scan_final(const int* __restrict__ cnt8,
                                                  const int* __restrict__ tsum,
                                                  int* __restrict__ offs, int n)
{
    const int lane = threadIdx.x & 63, wid = threadIdx.x >> 6;
    int tbase = 0;
    for (int i = 0; i < blockIdx.x; ++i) tbase += tsum[i];
    int base = blockIdx.x * SCAN_TILE + threadIdx.x * 16;
    int v[16]; int s = 0;
#pragma unroll
    for (int j = 0; j < 16; ++j) {
        int idx = base + j;
        int dv = 0;
        if (idx < n) {
            int4 a = ((const int4*)cnt8)[idx * 2];
            int4 b = ((const int4*)cnt8)[idx * 2 + 1];
            dv = a.x + a.y + a.z + a.w + b.x + b.y + b.z + b.w;
        }
        v[j] = dv; s += dv;
    }
    int inc = s;
    for (int d = 1; d < 64; d <<= 1) {
        int t = __shfl_up(inc, d, 64);
        if (lane >= d) inc += t;
    }
    __shared__ int wsum[4];
    if (lane == 63) wsum[wid] = inc;
    __syncthreads();
    int run = tbase + (inc - s);
    for (int k = 0; k < wid; ++k) run += wsum[k];
#pragma unroll
    for (int j = 0; j < 16; ++j) {
        int idx = base + j;
        if (idx < n) offs[idx] = run;
        run += v[j];
    }
}

// ---------------------------------------------------------------------------
// K5: scatter edges into dst-bucketed order.
// edgeP = int4 { (src*8+rel)*64, bits(1/cnt), dst, 0 } — one 16B scatter
// ---------------------------------------------------------------------------
__global__ __launch_bounds__(256) void scatter_kernel(const int* __restrict__ src,
                                                      const int* __restrict__ dst,
                                                      const int* __restrict__ et,
                                                      const int* __restrict__ offs,
                                                      int* __restrict__ cursor,
                                                      const int* __restrict__ cnt8,
                                                      int4* __restrict__ edgeP, int E)
{
    int e = blockIdx.x * 256 + threadIdx.x;
    if (e >= E) return;
    int d = dst[e], r = et[e], s = src[e];
    int c = cnt8[d * NREL + r];
    float inv = 1.0f / (float)(c > 1 ? c : 1);
    int pos = offs[d] + atomicAdd(&cursor[d], 1);
    edgeP[pos] = make_int4((s * NREL + r) * 64, __float_as_int(inv), d, 0);
}

// ---------------------------------------------------------------------------
// Persistent fused all-relation + root GEMM: [N,K] x [K,576], 9-way col split.
// Block (bx, by): ONE 4-tile col group (rel by<8, root by==8), LDS-staged once.
// Rel groups -> hr[n][g*64 + slot] bf16 (coalesced int2).
// Root group (L2OUT=false): aggF[n][slot] = root+bias f32 (coalesced float4)
//   — serves as the aggregation INIT (no zeroing, no separate yb).
// Root group (L2OUT=true): out[n][true_ch] = root+bias f32 (4 dword stores)
//   — d_out init; agg2's atomics add on top; fin2 pass eliminated.
// ---------------------------------------------------------------------------
template<int K, bool L2OUT>
__global__ __launch_bounds__(256) void gemm_mfma(const short* __restrict__ xf,
                                                 const short* __restrict__ Wf,
                                                 const float* __restrict__ bias,
                                                 short* __restrict__ hr,
                                                 float* __restrict__ rootF,
                                                 int N, int gblk)
{
    constexpr int NK = K / 32;
    __shared__ short lds[4 * NK * 512];

    const int w = threadIdx.x >> 6, lane = threadIdx.x & 63;
    const int kg = lane >> 4, lr = lane & 15;
    const int g = blockIdx.y;   // 0..7 = rel, 8 = root

    {
        const int4* gsrc = (const int4*)(Wf + (size_t)g * 4 * NK * 512);
        int4* ldst = (int4*)lds;
        for (int i = threadIdx.x; i < 4 * NK * 64; i += 256)
            ldst[i] = gsrc[i];
    }

    float b0 = bias[lr], b1 = bias[16 + lr], b2 = bias[32 + lr], b3 = bias[48 + lr];

    __syncthreads();

    for (int bx = blockIdx.x; bx < gblk; bx += gridDim.x) {
        const int rt = bx * 4 + w;

        bf16x8 afrag[NK];
        const short* ap = xf + ((size_t)rt * NK * 64 + lane) * 8;
#pragma unroll
        for (int ks = 0; ks < NK; ++ks)
            afrag[ks] = *(const bf16x8*)(ap + ks * 512);

        f32x4 acc[4];
#pragma unroll
        for (int t = 0; t < 4; ++t) acc[t] = (f32x4){0.f, 0.f, 0.f, 0.f};

#pragma unroll
        for (int tt = 0; tt < 4; ++tt) {
#pragma unroll
            for (int ks = 0; ks < NK; ++ks) {
                bf16x8 bfrag = *(const bf16x8*)(lds + (tt * NK + ks) * 512 + lane * 8);
                acc[tt] = __builtin_amdgcn_mfma_f32_16x16x32_bf16(afrag[ks], bfrag,
                                                                  acc[tt], 0, 0, 0);
            }
        }

        const int drow0 = rt * 16 + kg * 4;
#pragma unroll
        for (int r = 0; r < 4; ++r) {
            int dr = drow0 + r;
            if (dr >= N) break;
            if (g < 8) {
                int u0 = pack2bf(acc[0][r], acc[1][r]);
                int u1 = pack2bf(acc[2][r], acc[3][r]);
                *(int2*)(hr + (size_t)dr * 512 + g * 64 + lr * 4) = make_int2(u0, u1);
            } else if (!L2OUT) {
                // slot-order float4 init of aggF
                f32x4 o = {acc[0][r] + b0, acc[1][r] + b1, acc[2][r] + b2, acc[3][r] + b3};
                *(f32x4*)(rootF + (size_t)dr * 64 + lr * 4) = o;
            } else {
                // true-channel-order init of d_out
                rootF[(size_t)dr * 64 + lr]      = acc[0][r] + b0;
                rootF[(size_t)dr * 64 + 16 + lr] = acc[1][r] + b1;
                rootF[(size_t)dr * 64 + 32 + lr] = acc[2][r] + b2;
                rootF[(size_t)dr * 64 + 48 + lr] = acc[3][r] + b3;
            }
        }
    }
}

// ---------------------------------------------------------------------------
// Edge-chunk aggregate: each wave owns 32 CONSECUTIVE bucketed edges.
// All 32 gathers issued up front -> 32 outstanding 128B loads/wave.
// Wave-uniform segmented accumulate; dst-runs flushed via f32 HW atomics
// into gemm-initialized accF. PERM: atomic target uses true-channel index
// (layer 2 -> d_out directly).
// ---------------------------------------------------------------------------
template<bool PERM>
__global__ __launch_bounds__(256) void agg_chunk_kernel(
    const int4* __restrict__ edgeP, const short* __restrict__ hr,
    float* __restrict__ accF, int E)
{
    const int w = threadIdx.x >> 6, l = threadIdx.x & 63;
    const int base = (blockIdx.x * 4 + w) * 32;
    if (base >= E) return;
    const int nv = min(32, E - base);

    int idx = base + (l & 31);
    if (idx >= E) idx = E - 1;
    int4 pl = edgeP[idx];

    const unsigned short* hp = (const unsigned short*)hr;

    int g[32];
#pragma unroll
    for (int j = 0; j < 32; ++j) {
        int hoff = __shfl(pl.x, j);
        g[j] = hp[(size_t)hoff + l];
    }

    const int co = PERM ? ((l & 3) * 16 + (l >> 2)) : l;   // out index in row

    float acc = 0.f;
#pragma unroll
    for (int j = 0; j < 32; ++j) {
        if (j >= nv) break;
        float invj = __uint_as_float(__shfl(pl.y, j));
        acc = fmaf(bfval((unsigned short)g[j]), invj, acc);
        int dcur = __shfl(pl.z, j);
        int dnxt = __shfl(pl.z, (j + 1) & 31);
        if (j == nv - 1 || dnxt != dcur) {
            unsafeAtomicAdd(&accF[(size_t)dcur * 64 + co], acc);
            acc = 0.f;
        }
    }
}

// ---------------------------------------------------------------------------
// fin1: relu(aggF1) -> bf16 layer-2 A-fragment layout (slot -> true channel)
// ---------------------------------------------------------------------------
__global__ __launch_bounds__(256) void fin1_kernel(const float* __restrict__ aggF,
                                                   short* __restrict__ outB, int N)
{
    int i = blockIdx.x * 256 + threadIdx.x;
    if (i >= N * 64) return;
    int dst = i >> 6, l = i & 63;
    float v = fmaxf(aggF[i], 0.f);
    int tc = (l & 3) * 16 + (l >> 2);    // true channel
    int rt2 = dst >> 4, lr2 = dst & 15;
    int ks2 = tc >> 5, kg2 = (tc >> 3) & 3, e2 = tc & 7;
    outB[(((size_t)rt2 * 2 + ks2) * 64 + kg2 * 16 + lr2) * 8 + e2] = f2bf(v);
}

// ---------------------------------------------------------------------------
extern "C" void kernel_launch(void* const* d_in, const int* in_sizes, int n_in,
                              void* d_out, int out_size, void* d_ws, size_t ws_size,
                              hipStream_t stream)
{
    const float* x      = (const float*)d_in[0];
    const int*   ei     = (const int*)d_in[1];
    const int*   et     = (const int*)d_in[2];
    const float* basis1 = (const float*)d_in[3];
    const float* comp1  = (const float*)d_in[4];
    const float* root1  = (const float*)d_in[5];
    const float* bias1  = (const float*)d_in[6];
    const float* basis2 = (const float*)d_in[7];
    const float* comp2  = (const float*)d_in[8];
    const float* root2  = (const float*)d_in[9];
    const float* bias2  = (const float*)d_in[10];
    float* out = (float*)d_out;

    const int N = in_sizes[0] / 128;
    const int E = in_sizes[2];
    const int* src  = ei;
    const int* dstp = ei + E;

    const int gblk = (N + 63) / 64;
    const int NT   = gblk * 4;
    const int HB   = (E + 255) / 256;

    // -------- workspace carve (256B aligned) --------
    char* p = (char*)d_ws;
    auto carve = [&](size_t bytes) -> char* {
        char* q = p; p += (bytes + 255) & ~(size_t)255; return q;
    };
    int*   cursor  = (int*)carve((size_t)N * 4);            // zeroed
    int*   cnt8    = (int*)carve((size_t)N * NREL * 4);     // zeroed
    char*  zend    = p;
    float* aggF1   = (float*)carve((size_t)N * 64 * 4);     // init by gemm1 root
    int*   offs    = (int*)carve((size_t)(N + 1) * 4);
    int*   tsum    = (int*)carve(256 * 4);
    int4*  edgeP   = (int4*)carve((size_t)E * 16);
    short* Wf1     = (short*)carve((size_t)36 * 4 * 64 * 8 * 2);
    short* Wf2     = (short*)carve((size_t)36 * 2 * 64 * 8 * 2);
    short* xf1     = (short*)carve((size_t)NT * 4 * 64 * 8 * 2);
    short* xf2     = (short*)carve((size_t)NT * 2 * 64 * 8 * 2);
    short* hr      = (short*)carve((size_t)N * 512 * 2);

    const int zn16 = (int)((zend - (char*)cursor) / 16);
    const int ntiles = (N + SCAN_TILE - 1) / SCAN_TILE;
    const int CHB = (E + 127) / 128;    // agg chunk blocks (4 waves x 32 edges)
    const int FB  = (N * 64 + 255) / 256;

    // K1: zero (cursor, cnt8) + offs[N]=E
    zero_kernel<<<(zn16 + 255) / 256, 256, 0, stream>>>((int4*)cursor, zn16, offs + N, E);

    // K2: fused hist | wfrag1 | wfrag2 | afrag
    prep_hist_kernel<<<HB + 36 + 18 + NT, 256, 0, stream>>>(
        dstp, et, cnt8, basis1, root1, comp1, basis2, root2, comp2, x,
        Wf1, Wf2, xf1, E, N, NT, HB);

    // K3/K4: scan
    scan_part<<<ntiles, 256, 0, stream>>>(cnt8, tsum, N);
    scan_final<<<ntiles, 256, 0, stream>>>(cnt8, tsum, offs, N);

    // K5: scatter
    scatter_kernel<<<HB, 256, 0, stream>>>(src, dstp, et, offs, cursor,
                                           cnt8, edgeP, E);

    // ---- layer 1 ----
    gemm_mfma<128, false><<<dim3(256, 9), 256, 0, stream>>>(xf1, Wf1, bias1, hr,
                                                            aggF1, N, gblk);
    agg_chunk_kernel<false><<<CHB, 256, 0, stream>>>(edgeP, hr, aggF1, E);
    fin1_kernel<<<FB, 256, 0, stream>>>(aggF1, xf2, N);

    // ---- layer 2 ----
    gemm_mfma<64, true><<<dim3(256, 9), 256, 0, stream>>>(xf2, Wf2, bias2, hr,
                                                          out, N, gblk);
    agg_chunk_kernel<true><<<CHB, 256, 0, stream>>>(edgeP, hr, out, E);
}